// Round 5
// baseline (332.446 us; speedup 1.0000x reference)
//
#include <hip/hip_runtime.h>

// result = 0.25*sum(M) - 0.5*[ sum_{i<j} M_ij s_i s_j + sum_i M_ii s_i ]
//
// R8 = R7 (nt matrix loads, hoisted burst) + TWO adjacent rows per block.
// Cross-round evidence: read BW tracks bytes-in-flight per wave (R6 8-deep
// = 2.3 TB/s, R3 16-deep = 2.8, R7 16-deep+nt = 3.55). nt reads bypass L3
// -> full HBM latency per request -> BW = outstanding/latency. 16 matrix
// nt-loads per thread (24 KB/wave in flight, 1.5x R7) + tail amortized over
// 64 KB. Row pair (2b,2b+1) shares one diagonal vec4 index d=b>>1 -> single
// special-thread branch. s[] loads inline (L1/L2-hit, hidden by TLP) to
// keep VGPR ~100, 5 waves/SIMD, no spill (R4 lesson: watch WRITE_SIZE).

static constexpr int N_DIM  = 8192;
static constexpr int VPR    = N_DIM / 4;    // 2048 float4 per row
static constexpr int BLOCK  = 256;
static constexpr int ITERS  = VPR / BLOCK;  // 8 float4 per thread per row
static constexpr int GRID   = N_DIM / 2;    // 4096 blocks, 2 rows each
static constexpr int FBLOCK = 1024;

__device__ __forceinline__ float4 ntload4(const float4* p) {
    typedef float f32x4 __attribute__((ext_vector_type(4)));
    const f32x4 v = __builtin_nontemporal_load((const f32x4*)p);
    return make_float4(v.x, v.y, v.z, v.w);
}

__global__ __launch_bounds__(BLOCK) void ising_rowpair_kernel(
    const float4* __restrict__ mtx4,
    const float*  __restrict__ state,
    float*        __restrict__ partial)
{
    const int tid  = threadIdx.x;
    const int row0 = blockIdx.x << 1;      // even
    const int row1 = row0 | 1;
    const int d    = row0 >> 2;            // == row1>>2 (pair shares vec4 block)
    const float p0 = -0.5f * state[row0];
    const float p1 = -0.5f * state[row1];
    const float4* __restrict__ rp0 = mtx4 + (size_t)row0 * VPR;
    const float4* __restrict__ rp1 = mtx4 + (size_t)row1 * VPR;
    const float4* __restrict__ s4  = (const float4*)state;

    // 16 nt dwordx4 issued back-to-back: 24 KB (with s) in flight per wave.
    float4 m0[ITERS], m1[ITERS];
#pragma unroll
    for (int k = 0; k < ITERS; ++k)
        m0[k] = ntload4(rp0 + tid + (k << 8));
#pragma unroll
    for (int k = 0; k < ITERS; ++k)
        m1[k] = ntload4(rp1 + tid + (k << 8));

    float accA0 = 0.0f, accA1 = 0.0f;      // full-row sums (0.25*sum(M) term)
    float q0 = 0.0f, q1 = 0.0f;            // masked dots per row
#pragma unroll
    for (int k = 0; k < ITERS; ++k) {
        const int    v  = tid + (k << 8);
        const float4 a  = m0[k];
        const float4 b  = m1[k];
        const float4 sj = s4[v];           // inline: L1/L2-resident, reused chip-wide
        accA0 += (a.x + a.y) + (a.z + a.w);
        accA1 += (b.x + b.y) + (b.z + b.w);
        if (v > d) {                       // wave-uniform except 1 wave/block
            q0 = fmaf(a.x, sj.x, q0);
            q0 = fmaf(a.y, sj.y, q0);
            q0 = fmaf(a.z, sj.z, q0);
            q0 = fmaf(a.w, sj.w, q0);
            q1 = fmaf(b.x, sj.x, q1);
            q1 = fmaf(b.y, sj.y, q1);
            q1 = fmaf(b.z, sj.z, q1);
            q1 = fmaf(b.w, sj.w, q1);
        } else if (v == d) {               // exactly one thread per block
            const int j0 = v << 2;
            float w;
            // row0 weights: j>row0 ? s_j : (j==row0 ? 1 : 0)
            w = (j0 + 0 > row0) ? sj.x : ((j0 + 0 == row0) ? 1.0f : 0.0f);
            q0 = fmaf(a.x, w, q0);
            w = (j0 + 1 > row0) ? sj.y : ((j0 + 1 == row0) ? 1.0f : 0.0f);
            q0 = fmaf(a.y, w, q0);
            w = (j0 + 2 > row0) ? sj.z : ((j0 + 2 == row0) ? 1.0f : 0.0f);
            q0 = fmaf(a.z, w, q0);
            w = (j0 + 3 > row0) ? sj.w : ((j0 + 3 == row0) ? 1.0f : 0.0f);
            q0 = fmaf(a.w, w, q0);
            // row1 weights
            w = (j0 + 0 > row1) ? sj.x : ((j0 + 0 == row1) ? 1.0f : 0.0f);
            q1 = fmaf(b.x, w, q1);
            w = (j0 + 1 > row1) ? sj.y : ((j0 + 1 == row1) ? 1.0f : 0.0f);
            q1 = fmaf(b.y, w, q1);
            w = (j0 + 2 > row1) ? sj.z : ((j0 + 2 == row1) ? 1.0f : 0.0f);
            q1 = fmaf(b.z, w, q1);
            w = (j0 + 3 > row1) ? sj.w : ((j0 + 3 == row1) ? 1.0f : 0.0f);
            q1 = fmaf(b.w, w, q1);
        }
    }

    float acc = fmaf(0.25f, accA0 + accA1, fmaf(p0, q0, p1 * q1));

    // wave-64 shuffle reduction, then 4-entry LDS combine
    for (int off = 32; off > 0; off >>= 1)
        acc += __shfl_down(acc, off, 64);

    __shared__ float lds[BLOCK / 64];
    const int lane = tid & 63;
    const int wave = tid >> 6;
    if (lane == 0) lds[wave] = acc;
    __syncthreads();
    if (tid == 0)
        partial[blockIdx.x] = (lds[0] + lds[1]) + (lds[2] + lds[3]);
}

__global__ __launch_bounds__(FBLOCK) void ising_final_kernel(
    const float* __restrict__ partial,
    float*       __restrict__ out)
{
    float acc = 0.0f;
#pragma unroll
    for (int k = 0; k < GRID / FBLOCK; ++k)
        acc += partial[threadIdx.x + k * FBLOCK];

    for (int off = 32; off > 0; off >>= 1)
        acc += __shfl_down(acc, off, 64);

    __shared__ float lds[FBLOCK / 64];
    const int lane = threadIdx.x & 63;
    const int wave = threadIdx.x >> 6;
    if (lane == 0) lds[wave] = acc;
    __syncthreads();
    if (threadIdx.x == 0) {
        float sum = 0.0f;
#pragma unroll
        for (int w = 0; w < FBLOCK / 64; ++w) sum += lds[w];
        out[0] = sum;
    }
}

extern "C" void kernel_launch(void* const* d_in, const int* in_sizes, int n_in,
                              void* d_out, int out_size, void* d_ws, size_t ws_size,
                              hipStream_t stream) {
    const float* mtx   = (const float*)d_in[0];   // [8192*8192] fp32
    const float* state = (const float*)d_in[1];   // [8192] fp32
    float* out     = (float*)d_out;
    float* partial = (float*)d_ws;                // 4096 floats, fully overwritten

    ising_rowpair_kernel<<<GRID, BLOCK, 0, stream>>>((const float4*)mtx, state, partial);
    ising_final_kernel<<<1, FBLOCK, 0, stream>>>(partial, out);
}

// Round 6
// 331.530 us; speedup vs baseline: 1.0028x; 1.0028x over previous
//
#include <hip/hip_runtime.h>

// result = 0.25*sum(M) - 0.5*[ sum_{i<j} M_ij s_i s_j + sum_i M_ii s_i ]
//
// R9: LDS-DMA streaming probe. Evidence so far: VGPR-return reads cap at
// ~3.55 TB/s regardless of structure (R3 2.8, R6 2.3, R7 3.55, R8 24KB
// in-flight neutral) while the pure-write fill does 6.6 TB/s -> consistent
// with a per-CU in-flight read-line tracking cap (~80 x 64B lines / 375 ns
// = ~3.5 TB/s chip-wide). The untested mechanism is the global_load_lds DMA
// path (what AITER/HK stream through), which may use a deeper tracking
// structure. Block owns 16 rows, 2x32KB LDS double buffer, stage(next row)
// -> compute(cur row from LDS). __syncthreads drains vmcnt -> race-free;
// in-flight stays ~64KB/CU because each wait is for a 32KB batch.

static constexpr int N_DIM  = 8192;
static constexpr int VPR    = N_DIM / 4;    // 2048 float4 per row
static constexpr int BLOCK  = 256;
static constexpr int GRID   = 512;          // 2 blocks/CU (LDS-limited), 1 generation
static constexpr int RPB    = N_DIM / GRID; // 16 consecutive rows per block
static constexpr int FBLOCK = 512;

__device__ __forceinline__ void dma16(const void* g, void* l) {
    __builtin_amdgcn_global_load_lds(
        (const __attribute__((address_space(1))) void*)g,
        (__attribute__((address_space(3)))       void*)l,
        16, 0, 2 /* nt policy, match R7 */);
}

__global__ __launch_bounds__(BLOCK) void ising_dma_kernel(
    const float4* __restrict__ mtx4,
    const float*  __restrict__ state,
    float*        __restrict__ partial)
{
    __shared__ float4 buf[2][VPR];           // 2 x 32 KB = 64 KB
    const int tid = threadIdx.x;
    const int w   = tid >> 6;                // wave id (wave-uniform)

    const float4* __restrict__ s4 = (const float4*)state;
    float4 s[8];                             // state slice, loaded once
#pragma unroll
    for (int k = 0; k < 8; ++k)
        s[k] = s4[tid + (k << 8)];

    const int row0 = blockIdx.x * RPB;
    const float4* __restrict__ base = mtx4 + (size_t)row0 * VPR;

    // Prologue: stage row 0 into buf[0]. Per wave: 8 x 1KB DMA, lane-linear
    // global src == linear LDS dest (wave-uniform base + lane*16).
#pragma unroll
    for (int k = 0; k < 8; ++k)
        dma16(base + (k << 8) + tid, &buf[0][(k << 8) + (w << 6)]);

    float acc = 0.0f;

#pragma unroll 1
    for (int g = 0; g < RPB; ++g) {
        const int cur = g & 1;
        __syncthreads();                     // buf[cur] staged & buf[cur^1] free

        if (g + 1 < RPB) {                   // stage next row while computing cur
            const float4* nb = base + (size_t)(g + 1) * VPR;
#pragma unroll
            for (int k = 0; k < 8; ++k)
                dma16(nb + (k << 8) + tid, &buf[cur ^ 1][(k << 8) + (w << 6)]);
        }

        const int   row = row0 + g;
        const int   d   = row >> 2;          // diagonal's vec4 index
        const float p   = -0.5f * state[row];

        float accA = 0.0f, q0 = 0.0f, q1 = 0.0f;
#pragma unroll
        for (int k = 0; k < 8; ++k) {
            const int    v  = tid + (k << 8);
            const float4 mm = buf[cur][v];   // ds_read_b128
            const float4 sj = s[k];
            accA += (mm.x + mm.y) + (mm.z + mm.w);
            if (v > d) {                     // wave-uniform except 1 wave
                q0 = fmaf(mm.x, sj.x, q0);
                q1 = fmaf(mm.y, sj.y, q1);
                q0 = fmaf(mm.z, sj.z, q0);
                q1 = fmaf(mm.w, sj.w, q1);
            } else if (v == d) {             // exactly one thread
                const int j0 = v << 2;
                float ww;
                ww = (j0 + 0 > row) ? sj.x : ((j0 + 0 == row) ? 1.0f : 0.0f);
                q0 = fmaf(mm.x, ww, q0);
                ww = (j0 + 1 > row) ? sj.y : ((j0 + 1 == row) ? 1.0f : 0.0f);
                q1 = fmaf(mm.y, ww, q1);
                ww = (j0 + 2 > row) ? sj.z : ((j0 + 2 == row) ? 1.0f : 0.0f);
                q0 = fmaf(mm.z, ww, q0);
                ww = (j0 + 3 > row) ? sj.w : ((j0 + 3 == row) ? 1.0f : 0.0f);
                q1 = fmaf(mm.w, ww, q1);
            }
        }
        acc = fmaf(0.25f, accA, fmaf(p, q0 + q1, acc));
    }

    // One reduction per block (amortized over 16 rows).
    for (int off = 32; off > 0; off >>= 1)
        acc += __shfl_down(acc, off, 64);

    __shared__ float lds[BLOCK / 64];
    const int lane = tid & 63;
    if (lane == 0) lds[w] = acc;
    __syncthreads();
    if (tid == 0)
        partial[blockIdx.x] = (lds[0] + lds[1]) + (lds[2] + lds[3]);
}

__global__ __launch_bounds__(FBLOCK) void ising_final_kernel(
    const float* __restrict__ partial,
    float*       __restrict__ out)
{
    float acc = partial[threadIdx.x];        // GRID == FBLOCK == 512

    for (int off = 32; off > 0; off >>= 1)
        acc += __shfl_down(acc, off, 64);

    __shared__ float lds[FBLOCK / 64];
    const int lane = threadIdx.x & 63;
    const int wave = threadIdx.x >> 6;
    if (lane == 0) lds[wave] = acc;
    __syncthreads();
    if (threadIdx.x == 0) {
        float sum = 0.0f;
#pragma unroll
        for (int wv = 0; wv < FBLOCK / 64; ++wv) sum += lds[wv];
        out[0] = sum;
    }
}

extern "C" void kernel_launch(void* const* d_in, const int* in_sizes, int n_in,
                              void* d_out, int out_size, void* d_ws, size_t ws_size,
                              hipStream_t stream) {
    const float* mtx   = (const float*)d_in[0];   // [8192*8192] fp32
    const float* state = (const float*)d_in[1];   // [8192] fp32
    float* out     = (float*)d_out;
    float* partial = (float*)d_ws;                // 512 floats, fully overwritten

    ising_dma_kernel<<<GRID, BLOCK, 0, stream>>>((const float4*)mtx, state, partial);
    ising_final_kernel<<<1, FBLOCK, 0, stream>>>(partial, out);
}